// Round 10
// baseline (101.418 us; speedup 1.0000x reference)
//
#include <hip/hip_runtime.h>

// TSA_24936580121000 — fused temporal self-attention, MI355X gfx950. Round 10.
// R2/R8 operating point (WT=16, 512 thr, 70KB LDS, 2 blocks/CU, plain LB(512),
// clean traffic) restructured to TWO barriers total:
//   - qk scratch lives in the wave's own stage slot (read-before-write,
//     wave-internal, lgkmcnt-ordered -> no barrier)
//   - outT overwrites the wave's own dead stage slots (slot == position)
//   - only B1 (stage visible) and B2 (out visible before cross-wave P5)
// Between barriers waves run free, so the 2 resident blocks' memory phases
// slide against each other's compute -> higher HBM duty cycle.

#define C_  128
#define T_  16
#define H_  64
#define W_  64
#define HW_ (H_*W_)
#define CO_ 160          // 16 q + 16 k + 128 v
#define WT_ 16           // w positions per block
#define NBLK 1024        // 4 b * 64 h * 4 wtiles
#define THW (T_*H_*W_)

typedef float  f32x4  __attribute__((ext_vector_type(4)));
typedef short  bf16x4 __attribute__((ext_vector_type(4)));
typedef short  bf16x8 __attribute__((ext_vector_type(8)));

__device__ __forceinline__ unsigned short f2bf(float f) {
    union { float f; unsigned u; } v; v.f = f;
    unsigned r = v.u + 0x7fffu + ((v.u >> 16) & 1u);   // RNE
    return (unsigned short)(r >> 16);
}
__device__ __forceinline__ float bf2f(unsigned short s) {
    union { unsigned u; float f; } v; v.u = ((unsigned)s) << 16;
    return v.f;
}

// ---------------- prepack: fp32 weights -> bf16 W2[160][128], biases b2[160] ----
__global__ __launch_bounds__(256) void tsa_prepack(
        const float* __restrict__ qw, const float* __restrict__ qb,
        const float* __restrict__ kw, const float* __restrict__ kb,
        const float* __restrict__ vw, const float* __restrict__ vb,
        unsigned short* __restrict__ W2, float* __restrict__ b2) {
    int i = blockIdx.x * 256 + threadIdx.x;      // 80*256 == 20480 == 160*128
    int o = i >> 7, c = i & 127;
    float v = (o < 16) ? qw[o * C_ + c] : (o < 32) ? kw[(o - 16) * C_ + c]
                                                   : vw[(o - 32) * C_ + c];
    W2[i] = f2bf(v);
    if (i < CO_) b2[i] = (i < 16) ? qb[i] : (i < 32) ? kb[i - 16] : vb[i - 32];
}

// ---------------- LDS geometry (shorts) ----------------------------------------
// ONE region: [slot=16][t=16][c=128], slot-stride PS=2184, t-stride TS=136.
// Lifecycle per slot p (owned by wave p>>1):
//   x-stage [t][c]  ->  (afrag preload by owner)  ->  qk scratch (offset 0..640)
//   -> outT [t][c]  ->  P5 cross-wave read (after B2).
#define PS 2184
#define TS 136
#define IDX_X(pos, t, c)  ((pos) * PS + (t) * TS + (c))
#define QIDX(pos, qk, t, o) ((pos) * PS + (qk) * 320 + (t) * 20 + (o))
#define BUF_SH (T_ * PS)      // 34944 shorts = 69888 B -> 2 blocks/CU

// ---------------- main fused kernel --------------------------------------------
__global__ __launch_bounds__(512) void tsa_main(
        const float* __restrict__ x, const unsigned short* __restrict__ W2,
        const float* __restrict__ b2, const float* __restrict__ gamma,
        float* __restrict__ y) {

    __shared__ __align__(16) unsigned short buf[BUF_SH];

    // XCD-chunked swizzle (nwg=1024 % 8 == 0): 4 wtiles of one (b,h) row and
    // adjacent h share an XCD -> 128-512B spatial locality across resident blocks.
    int bid  = blockIdx.x;
    int work = (bid & 7) * (NBLK / 8) + (bid >> 3);
    int bh = work >> 2;
    int wt = work & 3;
    int b  = bh >> 6, h = bh & 63;
    int w0 = wt * WT_;

    const size_t base = (size_t)b * C_ * THW + (size_t)h * W_ + w0;
    const float* xb = x + base;
    float*       yb = y + base;

    const int tid = threadIdx.x;
    const int wq  = tid & 3;          // 16B segment within the 64B w-row
    const int cs  = tid >> 2;         // channel 0..127
    const float g = gamma[0];

    const int wv  = tid >> 6;         // wave 0..7 -> positions 2wv, 2wv+1
    const int lr  = tid & 15;
    const int grp = (tid & 63) >> 4;

    // ---- P1: stage x tile -> bf16 LDS [slot][t][c]; 16 loads in flight ------
    {
        const float* xcol = xb + (size_t)cs * THW + wq * 4;
        f32x4 xrA[8], xrB[8];
        #pragma unroll
        for (int t = 0; t < 8; ++t) xrA[t] = *(const f32x4*)(xcol + t * HW_);
        #pragma unroll
        for (int t = 0; t < 8; ++t) xrB[t] = *(const f32x4*)(xcol + (t + 8) * HW_);
        #pragma unroll
        for (int t = 0; t < 8; ++t) {
            #pragma unroll
            for (int e = 0; e < 4; ++e)
                buf[IDX_X(wq * 4 + e, t, cs)] = f2bf(xrA[t][e]);
        }
        #pragma unroll
        for (int t = 0; t < 8; ++t) {
            #pragma unroll
            for (int e = 0; e < 4; ++e)
                buf[IDX_X(wq * 4 + e, t + 8, cs)] = f2bf(xrB[t][e]);
        }
    }

    float biasv[10];
    #pragma unroll
    for (int nt = 0; nt < 10; ++nt) biasv[nt] = b2[nt * 16 + lr];

    __syncthreads();   // B1: stage visible (barrier 1 of 2)

    // ---- afrag preload: wave reads ONLY its own two slots --------------------
    bf16x8 afrag[2][4];
    #pragma unroll
    for (int p = 0; p < 2; ++p)
        #pragma unroll
        for (int ks = 0; ks < 4; ++ks)
            afrag[p][ks] = *(const bf16x8*)&buf[IDX_X(wv * 2 + p, lr, ks * 32 + grp * 8)];
    // slots 2wv, 2wv+1 are now dead x-data: reusable as this wave's scratch.

    // ---- P2: qkv projection (mfma 16x16x32 bf16), both positions share wf ----
    bf16x4 vreg[2][8];
    #pragma unroll
    for (int nt = 0; nt < 10; ++nt) {
        f32x4 acc0 = (f32x4){0.f, 0.f, 0.f, 0.f};
        f32x4 acc1 = (f32x4){0.f, 0.f, 0.f, 0.f};
        #pragma unroll
        for (int ks = 0; ks < 4; ++ks) {
            bf16x8 wf = *(const bf16x8*)&W2[(nt * 16 + lr) * C_ + ks * 32 + grp * 8];
            acc0 = __builtin_amdgcn_mfma_f32_16x16x32_bf16(afrag[0][ks], wf, acc0, 0, 0, 0);
            acc1 = __builtin_amdgcn_mfma_f32_16x16x32_bf16(afrag[1][ks], wf, acc1, 0, 0, 0);
        }
        if (nt < 2) {   // q/k -> wave-private scratch in OWN slots (no barrier)
            #pragma unroll
            for (int r = 0; r < 4; ++r) {
                buf[QIDX(wv * 2 + 0, nt, grp * 4 + r, lr)] = f2bf(acc0[r] + biasv[nt]);
                buf[QIDX(wv * 2 + 1, nt, grp * 4 + r, lr)] = f2bf(acc1[r] + biasv[nt]);
            }
        } else {        // v -> regs: proj D-layout == PV A-layout (same lane)
            bf16x4 p0, p1;
            #pragma unroll
            for (int r = 0; r < 4; ++r) {
                p0[r] = (short)f2bf(acc0[r] + biasv[nt]);
                p1[r] = (short)f2bf(acc1[r] + biasv[nt]);
            }
            vreg[0][nt - 2] = p0;
            vreg[1][nt - 2] = p1;
        }
    }

    // ---- P3: per position: scores^T -> softmax -> PV -> outT into own slot ---
    // (qk read-before-out-write within the wave is ordered by LDS dependences)
    #pragma unroll
    for (int p = 0; p < 2; ++p) {
        int pos = wv * 2 + p;
        bf16x4 kf = *(const bf16x4*)&buf[QIDX(pos, 1, lr, grp * 4)];
        bf16x4 qf = *(const bf16x4*)&buf[QIDX(pos, 0, lr, grp * 4)];
        f32x4 s = (f32x4){0.f, 0.f, 0.f, 0.f};
        s = __builtin_amdgcn_mfma_f32_16x16x16bf16_1k(kf, qf, s, 0, 0, 0);
        float mx = fmaxf(fmaxf(s[0], s[1]), fmaxf(s[2], s[3]));
        mx = fmaxf(mx, __shfl_xor(mx, 16));
        mx = fmaxf(mx, __shfl_xor(mx, 32));
        float e0 = __expf(s[0] - mx), e1 = __expf(s[1] - mx);
        float e2 = __expf(s[2] - mx), e3 = __expf(s[3] - mx);
        float sm = e0 + e1 + e2 + e3;
        sm += __shfl_xor(sm, 16);
        sm += __shfl_xor(sm, 32);
        float inv = 1.0f / sm;
        bf16x4 pf;
        pf[0] = (short)f2bf(e0 * inv); pf[1] = (short)f2bf(e1 * inv);
        pf[2] = (short)f2bf(e2 * inv); pf[3] = (short)f2bf(e3 * inv);
        #pragma unroll
        for (int ct = 0; ct < 8; ++ct) {
            f32x4 z = (f32x4){0.f, 0.f, 0.f, 0.f};
            z = __builtin_amdgcn_mfma_f32_16x16x16bf16_1k(vreg[p][ct], pf, z, 0, 0, 0);
            bf16x4 ob;
            #pragma unroll
            for (int r = 0; r < 4; ++r) ob[r] = (short)f2bf(z[r]);
            // outT[t=lr][c=ct*16+grp*4 ..+3] into the position's own slot
            *(bf16x4*)&buf[IDX_X(pos, lr, ct * 16 + grp * 4)] = ob;
        }
    }

    // ---- pre-issue first half of residual re-reads, then B2 ------------------
    const float* xrow = xb + (size_t)cs * THW + wq * 4;
    f32x4 xpA[8];
    #pragma unroll
    for (int t = 0; t < 8; ++t) xpA[t] = *(const f32x4*)(xrow + t * HW_);

    __syncthreads();   // B2: all outT visible (barrier 2 of 2)

    // ---- P5: y = gamma*out + x (exact fp32 residual) -------------------------
    {
        float* yrow = yb + (size_t)cs * THW + wq * 4;
        f32x4 xpB[8];
        #pragma unroll
        for (int t = 0; t < 8; ++t) xpB[t] = *(const f32x4*)(xrow + (t + 8) * HW_);
        #pragma unroll
        for (int t = 0; t < 8; ++t) {
            f32x4 rv;
            #pragma unroll
            for (int e = 0; e < 4; ++e)
                rv[e] = fmaf(g, bf2f(buf[IDX_X(wq * 4 + e, t, cs)]), xpA[t][e]);
            *(f32x4*)(yrow + t * HW_) = rv;
        }
        #pragma unroll
        for (int t = 0; t < 8; ++t) {
            f32x4 rv;
            #pragma unroll
            for (int e = 0; e < 4; ++e)
                rv[e] = fmaf(g, bf2f(buf[IDX_X(wq * 4 + e, t + 8, cs)]), xpB[t][e]);
            *(f32x4*)(yrow + (t + 8) * HW_) = rv;
        }
    }
}

// ---------------- launch --------------------------------------------------------
extern "C" void kernel_launch(void* const* d_in, const int* in_sizes, int n_in,
                              void* d_out, int out_size, void* d_ws, size_t ws_size,
                              hipStream_t stream) {
    const float* x  = (const float*)d_in[0];
    const float* qw = (const float*)d_in[1];
    const float* qb = (const float*)d_in[2];
    const float* kw = (const float*)d_in[3];
    const float* kb = (const float*)d_in[4];
    const float* vw = (const float*)d_in[5];
    const float* vb = (const float*)d_in[6];
    const float* gm = (const float*)d_in[7];
    float* y = (float*)d_out;

    unsigned short* W2 = (unsigned short*)d_ws;                  // 160*128 bf16
    float* b2 = (float*)((char*)d_ws + CO_ * C_ * sizeof(unsigned short));

    tsa_prepack<<<80, 256, 0, stream>>>(qw, qb, kw, kb, vw, vb, W2, b2);
    tsa_main<<<NBLK, 512, 0, stream>>>(x, W2, b2, gm, y);
}

// Round 11
// 99.845 us; speedup vs baseline: 1.0158x; 1.0158x over previous
//
#include <hip/hip_runtime.h>

// TSA_24936580121000 — fused temporal self-attention, MI355X gfx950. Round 11.
// = Round 10 (2 barriers, 2 blocks/CU, VGPR 92 clean, 101.4us) + ONE change:
// residual x carried in registers as bf16 (res[16], +32 VGPR) and the 134 MB
// global residual re-read DELETED (xpA/xpB gone, -32 VGPR). Tests the fabric-
// bandwidth theory: ~400 MB/launch through L2/L3 at ~4 TB/s is the wall; cutting
// the L3-hit re-read (invisible to FETCH_SIZE) should drop dur to ~75-88us.
// Spill canary: WRITE_SIZE must stay ~132 MB.

#define C_  128
#define T_  16
#define H_  64
#define W_  64
#define HW_ (H_*W_)
#define CO_ 160          // 16 q + 16 k + 128 v
#define WT_ 16           // w positions per block
#define NBLK 1024        // 4 b * 64 h * 4 wtiles
#define THW (T_*H_*W_)

typedef float  f32x4  __attribute__((ext_vector_type(4)));
typedef short  bf16x4 __attribute__((ext_vector_type(4)));
typedef short  bf16x8 __attribute__((ext_vector_type(8)));

__device__ __forceinline__ unsigned short f2bf(float f) {
    union { float f; unsigned u; } v; v.f = f;
    unsigned r = v.u + 0x7fffu + ((v.u >> 16) & 1u);   // RNE
    return (unsigned short)(r >> 16);
}
__device__ __forceinline__ float bf2f(unsigned short s) {
    union { unsigned u; float f; } v; v.u = ((unsigned)s) << 16;
    return v.f;
}

// ---------------- prepack: fp32 weights -> bf16 W2[160][128], biases b2[160] ----
__global__ __launch_bounds__(256) void tsa_prepack(
        const float* __restrict__ qw, const float* __restrict__ qb,
        const float* __restrict__ kw, const float* __restrict__ kb,
        const float* __restrict__ vw, const float* __restrict__ vb,
        unsigned short* __restrict__ W2, float* __restrict__ b2) {
    int i = blockIdx.x * 256 + threadIdx.x;      // 80*256 == 20480 == 160*128
    int o = i >> 7, c = i & 127;
    float v = (o < 16) ? qw[o * C_ + c] : (o < 32) ? kw[(o - 16) * C_ + c]
                                                   : vw[(o - 32) * C_ + c];
    W2[i] = f2bf(v);
    if (i < CO_) b2[i] = (i < 16) ? qb[i] : (i < 32) ? kb[i - 16] : vb[i - 32];
}

// ---------------- LDS geometry (shorts) ----------------------------------------
// ONE region: [slot=16][t=16][c=128], slot-stride PS=2184, t-stride TS=136.
// Slot p lifecycle (owner wave p>>1): x-stage -> afrag preload -> qk scratch
// (offset 0..640, wave-internal ds-ordered) -> outT [t][c] -> P5 cross-wave read.
#define PS 2184
#define TS 136
#define IDX_X(pos, t, c)  ((pos) * PS + (t) * TS + (c))
#define QIDX(pos, qk, t, o) ((pos) * PS + (qk) * 320 + (t) * 20 + (o))
#define BUF_SH (T_ * PS)      // 34944 shorts = 69888 B -> 2 blocks/CU

// ---------------- main fused kernel --------------------------------------------
__global__ __launch_bounds__(512) void tsa_main(
        const float* __restrict__ x, const unsigned short* __restrict__ W2,
        const float* __restrict__ b2, const float* __restrict__ gamma,
        float* __restrict__ y) {

    __shared__ __align__(16) unsigned short buf[BUF_SH];

    // XCD-chunked swizzle (nwg=1024 % 8 == 0): 4 wtiles of one (b,h) row and
    // adjacent h share an XCD -> L2 line sharing for the 64B write pieces.
    int bid  = blockIdx.x;
    int work = (bid & 7) * (NBLK / 8) + (bid >> 3);
    int bh = work >> 2;
    int wt = work & 3;
    int b  = bh >> 6, h = bh & 63;
    int w0 = wt * WT_;

    const size_t base = (size_t)b * C_ * THW + (size_t)h * W_ + w0;
    const float* xb = x + base;
    float*       yb = y + base;

    const int tid = threadIdx.x;
    const int wq  = tid & 3;          // 16B segment within the 64B w-row
    const int cs  = tid >> 2;         // channel 0..127
    const float g = gamma[0];

    const int wv  = tid >> 6;         // wave 0..7 -> positions 2wv, 2wv+1
    const int lr  = tid & 15;
    const int grp = (tid & 63) >> 4;

    // ---- P1: stage x -> bf16 LDS [slot][t][c]; keep bf16 residual in regs ---
    bf16x4 res[16];                   // +32 VGPR, lives to P5 (replaces re-read)
    {
        const float* xcol = xb + (size_t)cs * THW + wq * 4;
        f32x4 xrA[8], xrB[8];
        #pragma unroll
        for (int t = 0; t < 8; ++t) xrA[t] = *(const f32x4*)(xcol + t * HW_);
        #pragma unroll
        for (int t = 0; t < 8; ++t) xrB[t] = *(const f32x4*)(xcol + (t + 8) * HW_);
        #pragma unroll
        for (int t = 0; t < 8; ++t) {
            #pragma unroll
            for (int e = 0; e < 4; ++e) {
                unsigned short u = f2bf(xrA[t][e]);
                res[t][e] = (short)u;
                buf[IDX_X(wq * 4 + e, t, cs)] = u;
            }
        }
        #pragma unroll
        for (int t = 0; t < 8; ++t) {
            #pragma unroll
            for (int e = 0; e < 4; ++e) {
                unsigned short u = f2bf(xrB[t][e]);
                res[t + 8][e] = (short)u;
                buf[IDX_X(wq * 4 + e, t + 8, cs)] = u;
            }
        }
    }

    float biasv[10];
    #pragma unroll
    for (int nt = 0; nt < 10; ++nt) biasv[nt] = b2[nt * 16 + lr];

    __syncthreads();   // B1: stage visible (barrier 1 of 2)

    // ---- afrag preload: wave reads ONLY its own two slots --------------------
    bf16x8 afrag[2][4];
    #pragma unroll
    for (int p = 0; p < 2; ++p)
        #pragma unroll
        for (int ks = 0; ks < 4; ++ks)
            afrag[p][ks] = *(const bf16x8*)&buf[IDX_X(wv * 2 + p, lr, ks * 32 + grp * 8)];
    // slots 2wv, 2wv+1 are now dead x-data: reusable as this wave's scratch.

    // ---- P2: qkv projection (mfma 16x16x32 bf16), both positions share wf ----
    bf16x4 vreg[2][8];
    #pragma unroll
    for (int nt = 0; nt < 10; ++nt) {
        f32x4 acc0 = (f32x4){0.f, 0.f, 0.f, 0.f};
        f32x4 acc1 = (f32x4){0.f, 0.f, 0.f, 0.f};
        #pragma unroll
        for (int ks = 0; ks < 4; ++ks) {
            bf16x8 wf = *(const bf16x8*)&W2[(nt * 16 + lr) * C_ + ks * 32 + grp * 8];
            acc0 = __builtin_amdgcn_mfma_f32_16x16x32_bf16(afrag[0][ks], wf, acc0, 0, 0, 0);
            acc1 = __builtin_amdgcn_mfma_f32_16x16x32_bf16(afrag[1][ks], wf, acc1, 0, 0, 0);
        }
        if (nt < 2) {   // q/k -> wave-private scratch in OWN slots (no barrier)
            #pragma unroll
            for (int r = 0; r < 4; ++r) {
                buf[QIDX(wv * 2 + 0, nt, grp * 4 + r, lr)] = f2bf(acc0[r] + biasv[nt]);
                buf[QIDX(wv * 2 + 1, nt, grp * 4 + r, lr)] = f2bf(acc1[r] + biasv[nt]);
            }
        } else {        // v -> regs: proj D-layout == PV A-layout (same lane)
            bf16x4 p0, p1;
            #pragma unroll
            for (int r = 0; r < 4; ++r) {
                p0[r] = (short)f2bf(acc0[r] + biasv[nt]);
                p1[r] = (short)f2bf(acc1[r] + biasv[nt]);
            }
            vreg[0][nt - 2] = p0;
            vreg[1][nt - 2] = p1;
        }
    }

    // ---- P3: per position: scores^T -> softmax -> PV -> outT into own slot ---
    #pragma unroll
    for (int p = 0; p < 2; ++p) {
        int pos = wv * 2 + p;
        bf16x4 kf = *(const bf16x4*)&buf[QIDX(pos, 1, lr, grp * 4)];
        bf16x4 qf = *(const bf16x4*)&buf[QIDX(pos, 0, lr, grp * 4)];
        f32x4 s = (f32x4){0.f, 0.f, 0.f, 0.f};
        s = __builtin_amdgcn_mfma_f32_16x16x16bf16_1k(kf, qf, s, 0, 0, 0);
        float mx = fmaxf(fmaxf(s[0], s[1]), fmaxf(s[2], s[3]));
        mx = fmaxf(mx, __shfl_xor(mx, 16));
        mx = fmaxf(mx, __shfl_xor(mx, 32));
        float e0 = __expf(s[0] - mx), e1 = __expf(s[1] - mx);
        float e2 = __expf(s[2] - mx), e3 = __expf(s[3] - mx);
        float sm = e0 + e1 + e2 + e3;
        sm += __shfl_xor(sm, 16);
        sm += __shfl_xor(sm, 32);
        float inv = 1.0f / sm;
        bf16x4 pf;
        pf[0] = (short)f2bf(e0 * inv); pf[1] = (short)f2bf(e1 * inv);
        pf[2] = (short)f2bf(e2 * inv); pf[3] = (short)f2bf(e3 * inv);
        #pragma unroll
        for (int ct = 0; ct < 8; ++ct) {
            f32x4 z = (f32x4){0.f, 0.f, 0.f, 0.f};
            z = __builtin_amdgcn_mfma_f32_16x16x16bf16_1k(vreg[p][ct], pf, z, 0, 0, 0);
            bf16x4 ob;
            #pragma unroll
            for (int r = 0; r < 4; ++r) ob[r] = (short)f2bf(z[r]);
            // outT[t=lr][c=ct*16+grp*4 ..+3] into the position's own slot
            *(bf16x4*)&buf[IDX_X(pos, lr, ct * 16 + grp * 4)] = ob;
        }
    }

    __syncthreads();   // B2: all outT visible (barrier 2 of 2)

    // ---- P5: y = gamma*out + res (bf16 residual, NO global reads) ------------
    {
        float* yrow = yb + (size_t)cs * THW + wq * 4;
        #pragma unroll
        for (int t = 0; t < T_; ++t) {
            f32x4 rv;
            #pragma unroll
            for (int e = 0; e < 4; ++e)
                rv[e] = fmaf(g, bf2f(buf[IDX_X(wq * 4 + e, t, cs)]),
                             bf2f((unsigned short)res[t][e]));
            *(f32x4*)(yrow + t * HW_) = rv;
        }
    }
}

// ---------------- launch --------------------------------------------------------
extern "C" void kernel_launch(void* const* d_in, const int* in_sizes, int n_in,
                              void* d_out, int out_size, void* d_ws, size_t ws_size,
                              hipStream_t stream) {
    const float* x  = (const float*)d_in[0];
    const float* qw = (const float*)d_in[1];
    const float* qb = (const float*)d_in[2];
    const float* kw = (const float*)d_in[3];
    const float* kb = (const float*)d_in[4];
    const float* vw = (const float*)d_in[5];
    const float* vb = (const float*)d_in[6];
    const float* gm = (const float*)d_in[7];
    float* y = (float*)d_out;

    unsigned short* W2 = (unsigned short*)d_ws;                  // 160*128 bf16
    float* b2 = (float*)((char*)d_ws + CO_ * C_ * sizeof(unsigned short));

    tsa_prepack<<<80, 256, 0, stream>>>(qw, qb, kw, kb, vw, vb, W2, b2);
    tsa_main<<<NBLK, 512, 0, stream>>>(x, W2, b2, gm, y);
}

// Round 12
// 99.438 us; speedup vs baseline: 1.0199x; 1.0041x over previous
//
#include <hip/hip_runtime.h>

// TSA_24936580121000 — fused temporal self-attention, MI355X gfx950. Round 12.
// = Round 9 (WT=32: 128B global pieces, best measured byte-rate 3.1 TB/s) with
// the register spill removed: P5 re-read goes rolling 8-deep (was flat 16 =
// 64 transient VGPRs -> pushed peak to 128 and spilled ~34 MB of writes).
// Everything else identical to R9: 512 thr plain LB(512), wave-private qk
// scratch, outT into the position's own dead stage slot, 2 barriers,
// XOR-swizzled stage c, XCD-chunked block swizzle, exact fp32 residual re-read.

#define C_  128
#define T_  16
#define H_  64
#define W_  64
#define HW_ (H_*W_)
#define CO_ 160          // 16 q + 16 k + 128 v
#define WT_ 32           // w positions per block
#define NBLK 512         // 4 b * 64 h * 2 wtiles
#define THW (T_*H_*W_)

typedef float  f32x4  __attribute__((ext_vector_type(4)));
typedef short  bf16x4 __attribute__((ext_vector_type(4)));
typedef short  bf16x8 __attribute__((ext_vector_type(8)));

__device__ __forceinline__ unsigned short f2bf(float f) {
    union { float f; unsigned u; } v; v.f = f;
    unsigned r = v.u + 0x7fffu + ((v.u >> 16) & 1u);   // RNE
    return (unsigned short)(r >> 16);
}
__device__ __forceinline__ float bf2f(unsigned short s) {
    union { unsigned u; float f; } v; v.u = ((unsigned)s) << 16;
    return v.f;
}

// ---------------- prepack: fp32 weights -> bf16 W2[160][128], biases b2[160] ----
__global__ __launch_bounds__(256) void tsa_prepack(
        const float* __restrict__ qw, const float* __restrict__ qb,
        const float* __restrict__ kw, const float* __restrict__ kb,
        const float* __restrict__ vw, const float* __restrict__ vb,
        unsigned short* __restrict__ W2, float* __restrict__ b2) {
    int i = blockIdx.x * 256 + threadIdx.x;      // 80*256 == 20480 == 160*128
    int o = i >> 7, c = i & 127;
    float v = (o < 16) ? qw[o * C_ + c] : (o < 32) ? kw[(o - 16) * C_ + c]
                                                   : vw[(o - 32) * C_ + c];
    W2[i] = f2bf(v);
    if (i < CO_) b2[i] = (i < 16) ? qb[i] : (i < 32) ? kb[i - 16] : vb[i - 32];
}

// ---------------- LDS geometry (shorts) ----------------------------------------
// stage/out (time-shared PER SLOT): [pos=32][t=16][c=128 swz] pos-stride 2184,
//   t-stride 136. c stored XOR-swizzled: loc = c ^ ((pos>>2)<<3).
// qkscr: wave-private [wv=8][qk=2][t=16][o-stride 20]  (no barrier needed)
// bias:  f32[160]
#define PS 2184
#define TS 136
#define IDX_X(pos, t, c)   ((pos) * PS + (t) * TS + (c))
#define QOFF 69888
#define QIDX(wv, qk, t, o) (QOFF + (wv) * 640 + (qk) * 320 + (t) * 20 + (o))
#define BIAS_OFF 75008
#define BUF_SH 75328          // 150656 B <= 160 KiB -> 1 block/CU

// ---------------- main fused kernel --------------------------------------------
__global__ __launch_bounds__(512) void tsa_main(
        const float* __restrict__ x, const unsigned short* __restrict__ W2,
        const float* __restrict__ b2, const float* __restrict__ gamma,
        float* __restrict__ y) {

    __shared__ __align__(16) unsigned short buf[BUF_SH];
    float* bias_lds = (float*)&buf[BIAS_OFF];

    // XCD-chunked swizzle (nwg=512 % 8 == 0)
    int bid  = blockIdx.x;
    int work = (bid & 7) * (NBLK / 8) + (bid >> 3);
    int bh = work >> 1;
    int wt = work & 1;
    int b  = bh >> 6, h = bh & 63;
    int w0 = wt * WT_;

    const size_t base = (size_t)b * C_ * THW + (size_t)h * W_ + w0;
    const float* xb = x + base;
    float*       yb = y + base;

    const int tid = threadIdx.x;
    const int seg = tid & 7;          // 16B segment of the 128B w-row
    const int cs0 = tid >> 3;         // channel 0..63 (+64 on round 1)
    const float g = gamma[0];

    const int wv  = tid >> 6;         // wave 0..7 -> positions wv*4 .. wv*4+3
    const int lr  = tid & 15;
    const int grp = (tid & 63) >> 4;

    if (tid < CO_) bias_lds[tid] = b2[tid];

    // ---- P1: stage x tile -> bf16 LDS [pos][t][c-swz]; 128B read pieces -----
    #pragma unroll
    for (int r = 0; r < 2; ++r) {
        const int cs  = cs0 + 64 * r;
        const int loc = cs ^ (seg << 3);
        const float* xcol = xb + (size_t)cs * THW + seg * 4;
        f32x4 xa[8];
        #pragma unroll
        for (int t = 0; t < 8; ++t) xa[t] = *(const f32x4*)(xcol + t * HW_);
        #pragma unroll
        for (int t = 0; t < 8; ++t)
            #pragma unroll
            for (int e = 0; e < 4; ++e)
                buf[IDX_X(seg * 4 + e, t, loc)] = f2bf(xa[t][e]);
        #pragma unroll
        for (int t = 0; t < 8; ++t) xa[t] = *(const f32x4*)(xcol + (t + 8) * HW_);
        #pragma unroll
        for (int t = 0; t < 8; ++t)
            #pragma unroll
            for (int e = 0; e < 4; ++e)
                buf[IDX_X(seg * 4 + e, t + 8, loc)] = f2bf(xa[t][e]);
    }
    __syncthreads();   // B1 (one of only two barriers)

    // ---- per-wave: project + attend 4 positions, all wave-local -------------
    const int swz = wv << 3;          // pos>>2 == wv for this wave's positions
    for (int pp = 0; pp < 4; ++pp) {
        const int pos = wv * 4 + pp;

        // afrag preload; after this the slot is dead (only this wave reads it)
        bf16x8 afrag[4];
        #pragma unroll
        for (int ks = 0; ks < 4; ++ks)
            afrag[ks] = *(const bf16x8*)&buf[IDX_X(pos, lr, (ks * 32 + grp * 8) ^ swz)];

        // qkv projection (mfma 16x16x32): q/k -> wave-private LDS scratch,
        // v -> regs (proj D-layout == PV A-layout for the same lane)
        bf16x4 vreg[8];
        #pragma unroll
        for (int nt = 0; nt < 10; ++nt) {
            f32x4 acc = (f32x4){0.f, 0.f, 0.f, 0.f};
            #pragma unroll
            for (int ks = 0; ks < 4; ++ks) {
                bf16x8 wf = *(const bf16x8*)&W2[(nt * 16 + lr) * C_ + ks * 32 + grp * 8];
                acc = __builtin_amdgcn_mfma_f32_16x16x32_bf16(afrag[ks], wf, acc, 0, 0, 0);
            }
            float bv = bias_lds[nt * 16 + lr];
            if (nt < 2) {
                #pragma unroll
                for (int rr = 0; rr < 4; ++rr)
                    buf[QIDX(wv, nt, grp * 4 + rr, lr)] = f2bf(acc[rr] + bv);
            } else {
                bf16x4 pk;
                #pragma unroll
                for (int rr = 0; rr < 4; ++rr) pk[rr] = (short)f2bf(acc[rr] + bv);
                vreg[nt - 2] = pk;
            }
        }

        // scores^T -> softmax -> PV (wave-local; lgkmcnt orders qkscr)
        bf16x4 kf = *(const bf16x4*)&buf[QIDX(wv, 1, lr, grp * 4)];
        bf16x4 qf = *(const bf16x4*)&buf[QIDX(wv, 0, lr, grp * 4)];
        f32x4 s = (f32x4){0.f, 0.f, 0.f, 0.f};
        s = __builtin_amdgcn_mfma_f32_16x16x16bf16_1k(kf, qf, s, 0, 0, 0);
        float mx = fmaxf(fmaxf(s[0], s[1]), fmaxf(s[2], s[3]));
        mx = fmaxf(mx, __shfl_xor(mx, 16));
        mx = fmaxf(mx, __shfl_xor(mx, 32));
        float e0 = __expf(s[0] - mx), e1 = __expf(s[1] - mx);
        float e2 = __expf(s[2] - mx), e3 = __expf(s[3] - mx);
        float sm = e0 + e1 + e2 + e3;
        sm += __shfl_xor(sm, 16);
        sm += __shfl_xor(sm, 32);
        float inv = 1.0f / sm;
        bf16x4 pf;
        pf[0] = (short)f2bf(e0 * inv); pf[1] = (short)f2bf(e1 * inv);
        pf[2] = (short)f2bf(e2 * inv); pf[3] = (short)f2bf(e3 * inv);

        // outT -> the position's own (dead) stage slot, same swizzle
        #pragma unroll
        for (int ct = 0; ct < 8; ++ct) {
            f32x4 z = (f32x4){0.f, 0.f, 0.f, 0.f};
            z = __builtin_amdgcn_mfma_f32_16x16x16bf16_1k(vreg[ct], pf, z, 0, 0, 0);
            bf16x4 ob;
            #pragma unroll
            for (int rr = 0; rr < 4; ++rr) ob[rr] = (short)f2bf(z[rr]);
            *(bf16x4*)&buf[IDX_X(pos, lr, (ct * 16 + grp * 4) ^ swz)] = ob;
        }
    }
    __syncthreads();   // B2: all outT slots visible

    // ---- P5: y = gamma*out + x (exact fp32 residual); 128B pieces, ----------
    // rolling 8-deep re-read halves (was flat 16 -> 64 transient VGPRs, spill)
    #pragma unroll
    for (int r = 0; r < 2; ++r) {
        const int cs  = cs0 + 64 * r;
        const int loc = cs ^ (seg << 3);   // matches writer: pos>>2 == seg here
        const float* xrow = xb + (size_t)cs * THW + seg * 4;
        float*       yrow = yb + (size_t)cs * THW + seg * 4;
        #pragma unroll
        for (int half = 0; half < 2; ++half) {
            const int t0 = half * 8;
            f32x4 xa[8];
            #pragma unroll
            for (int t = 0; t < 8; ++t) xa[t] = *(const f32x4*)(xrow + (t0 + t) * HW_);
            #pragma unroll
            for (int t = 0; t < 8; ++t) {
                f32x4 rv;
                #pragma unroll
                for (int e = 0; e < 4; ++e)
                    rv[e] = fmaf(g, bf2f(buf[IDX_X(seg * 4 + e, t0 + t, loc)]), xa[t][e]);
                *(f32x4*)(yrow + (t0 + t) * HW_) = rv;
            }
        }
    }
}

// ---------------- launch --------------------------------------------------------
extern "C" void kernel_launch(void* const* d_in, const int* in_sizes, int n_in,
                              void* d_out, int out_size, void* d_ws, size_t ws_size,
                              hipStream_t stream) {
    const float* x  = (const float*)d_in[0];
    const float* qw = (const float*)d_in[1];
    const float* qb = (const float*)d_in[2];
    const float* kw = (const float*)d_in[3];
    const float* kb = (const float*)d_in[4];
    const float* vw = (const float*)d_in[5];
    const float* vb = (const float*)d_in[6];
    const float* gm = (const float*)d_in[7];
    float* y = (float*)d_out;

    unsigned short* W2 = (unsigned short*)d_ws;                  // 160*128 bf16
    float* b2 = (float*)((char*)d_ws + CO_ * C_ * sizeof(unsigned short));

    tsa_prepack<<<80, 256, 0, stream>>>(qw, qb, kw, kb, vw, vb, W2, b2);
    tsa_main<<<NBLK, 512, 0, stream>>>(x, W2, b2, gm, y);
}

// Round 13
// 88.084 us; speedup vs baseline: 1.1514x; 1.1289x over previous
//
#include <hip/hip_runtime.h>

// TSA_24936580121000 — fused temporal self-attention, MI355X gfx950. Round 13.
// = Round 12 with ONE change: the outer c-half loops (r=0,1) in P1 and P5 are
// SERIAL (no #pragma unroll). R12's unroll let the compiler interleave both
// halves' 8-deep load batches -> 64 transient VGPRs -> peak >128 -> ~32 MB of
// scratch spill (WRITE 164 vs 132 ideal). Serializing caps transients at 32.
// All register arrays inside remain constant-indexed (no dynamic-index scratch).

#define C_  128
#define T_  16
#define H_  64
#define W_  64
#define HW_ (H_*W_)
#define CO_ 160          // 16 q + 16 k + 128 v
#define WT_ 32           // w positions per block
#define NBLK 512         // 4 b * 64 h * 2 wtiles
#define THW (T_*H_*W_)

typedef float  f32x4  __attribute__((ext_vector_type(4)));
typedef short  bf16x4 __attribute__((ext_vector_type(4)));
typedef short  bf16x8 __attribute__((ext_vector_type(8)));

__device__ __forceinline__ unsigned short f2bf(float f) {
    union { float f; unsigned u; } v; v.f = f;
    unsigned r = v.u + 0x7fffu + ((v.u >> 16) & 1u);   // RNE
    return (unsigned short)(r >> 16);
}
__device__ __forceinline__ float bf2f(unsigned short s) {
    union { unsigned u; float f; } v; v.u = ((unsigned)s) << 16;
    return v.f;
}

// ---------------- prepack: fp32 weights -> bf16 W2[160][128], biases b2[160] ----
__global__ __launch_bounds__(256) void tsa_prepack(
        const float* __restrict__ qw, const float* __restrict__ qb,
        const float* __restrict__ kw, const float* __restrict__ kb,
        const float* __restrict__ vw, const float* __restrict__ vb,
        unsigned short* __restrict__ W2, float* __restrict__ b2) {
    int i = blockIdx.x * 256 + threadIdx.x;      // 80*256 == 20480 == 160*128
    int o = i >> 7, c = i & 127;
    float v = (o < 16) ? qw[o * C_ + c] : (o < 32) ? kw[(o - 16) * C_ + c]
                                                   : vw[(o - 32) * C_ + c];
    W2[i] = f2bf(v);
    if (i < CO_) b2[i] = (i < 16) ? qb[i] : (i < 32) ? kb[i - 16] : vb[i - 32];
}

// ---------------- LDS geometry (shorts) ----------------------------------------
// stage/out (time-shared PER SLOT): [pos=32][t=16][c=128 swz] pos-stride 2184,
//   t-stride 136. c stored XOR-swizzled: loc = c ^ ((pos>>2)<<3).
// qkscr: wave-private [wv=8][qk=2][t=16][o-stride 20]  (no barrier needed)
// bias:  f32[160]
#define PS 2184
#define TS 136
#define IDX_X(pos, t, c)   ((pos) * PS + (t) * TS + (c))
#define QOFF 69888
#define QIDX(wv, qk, t, o) (QOFF + (wv) * 640 + (qk) * 320 + (t) * 20 + (o))
#define BIAS_OFF 75008
#define BUF_SH 75328          // 150656 B <= 160 KiB -> 1 block/CU

// ---------------- main fused kernel --------------------------------------------
__global__ __launch_bounds__(512) void tsa_main(
        const float* __restrict__ x, const unsigned short* __restrict__ W2,
        const float* __restrict__ b2, const float* __restrict__ gamma,
        float* __restrict__ y) {

    __shared__ __align__(16) unsigned short buf[BUF_SH];
    float* bias_lds = (float*)&buf[BIAS_OFF];

    // XCD-chunked swizzle (nwg=512 % 8 == 0)
    int bid  = blockIdx.x;
    int work = (bid & 7) * (NBLK / 8) + (bid >> 3);
    int bh = work >> 1;
    int wt = work & 1;
    int b  = bh >> 6, h = bh & 63;
    int w0 = wt * WT_;

    const size_t base = (size_t)b * C_ * THW + (size_t)h * W_ + w0;
    const float* xb = x + base;
    float*       yb = y + base;

    const int tid = threadIdx.x;
    const int seg = tid & 7;          // 16B segment of the 128B w-row
    const int cs0 = tid >> 3;         // channel 0..63 (+64 on second half)
    const float g = gamma[0];

    const int wv  = tid >> 6;         // wave 0..7 -> positions wv*4 .. wv*4+3
    const int lr  = tid & 15;
    const int grp = (tid & 63) >> 4;

    if (tid < CO_) bias_lds[tid] = b2[tid];

    // ---- P1: stage x tile -> bf16 LDS [pos][t][c-swz]; 128B read pieces -----
    // SERIAL r-loop: one 8-deep batch in flight at a time (32 transient VGPRs).
    for (int r = 0; r < 2; ++r) {
        const int cs  = cs0 + 64 * r;
        const int loc = cs ^ (seg << 3);
        const float* xcol = xb + (size_t)cs * THW + seg * 4;
        f32x4 xa[8];
        #pragma unroll
        for (int t = 0; t < 8; ++t) xa[t] = *(const f32x4*)(xcol + t * HW_);
        #pragma unroll
        for (int t = 0; t < 8; ++t)
            #pragma unroll
            for (int e = 0; e < 4; ++e)
                buf[IDX_X(seg * 4 + e, t, loc)] = f2bf(xa[t][e]);
        #pragma unroll
        for (int t = 0; t < 8; ++t) xa[t] = *(const f32x4*)(xcol + (t + 8) * HW_);
        #pragma unroll
        for (int t = 0; t < 8; ++t)
            #pragma unroll
            for (int e = 0; e < 4; ++e)
                buf[IDX_X(seg * 4 + e, t + 8, loc)] = f2bf(xa[t][e]);
    }
    __syncthreads();   // B1 (one of only two barriers)

    // ---- per-wave: project + attend 4 positions, all wave-local -------------
    const int swz = wv << 3;          // pos>>2 == wv for this wave's positions
    for (int pp = 0; pp < 4; ++pp) {
        const int pos = wv * 4 + pp;

        // afrag preload; after this the slot is dead (only this wave reads it)
        bf16x8 afrag[4];
        #pragma unroll
        for (int ks = 0; ks < 4; ++ks)
            afrag[ks] = *(const bf16x8*)&buf[IDX_X(pos, lr, (ks * 32 + grp * 8) ^ swz)];

        // qkv projection (mfma 16x16x32): q/k -> wave-private LDS scratch,
        // v -> regs (proj D-layout == PV A-layout for the same lane)
        bf16x4 vreg[8];
        #pragma unroll
        for (int nt = 0; nt < 10; ++nt) {
            f32x4 acc = (f32x4){0.f, 0.f, 0.f, 0.f};
            #pragma unroll
            for (int ks = 0; ks < 4; ++ks) {
                bf16x8 wf = *(const bf16x8*)&W2[(nt * 16 + lr) * C_ + ks * 32 + grp * 8];
                acc = __builtin_amdgcn_mfma_f32_16x16x32_bf16(afrag[ks], wf, acc, 0, 0, 0);
            }
            float bv = bias_lds[nt * 16 + lr];
            if (nt < 2) {
                #pragma unroll
                for (int rr = 0; rr < 4; ++rr)
                    buf[QIDX(wv, nt, grp * 4 + rr, lr)] = f2bf(acc[rr] + bv);
            } else {
                bf16x4 pk;
                #pragma unroll
                for (int rr = 0; rr < 4; ++rr) pk[rr] = (short)f2bf(acc[rr] + bv);
                vreg[nt - 2] = pk;
            }
        }

        // scores^T -> softmax -> PV (wave-local; lgkmcnt orders qkscr)
        bf16x4 kf = *(const bf16x4*)&buf[QIDX(wv, 1, lr, grp * 4)];
        bf16x4 qf = *(const bf16x4*)&buf[QIDX(wv, 0, lr, grp * 4)];
        f32x4 s = (f32x4){0.f, 0.f, 0.f, 0.f};
        s = __builtin_amdgcn_mfma_f32_16x16x16bf16_1k(kf, qf, s, 0, 0, 0);
        float mx = fmaxf(fmaxf(s[0], s[1]), fmaxf(s[2], s[3]));
        mx = fmaxf(mx, __shfl_xor(mx, 16));
        mx = fmaxf(mx, __shfl_xor(mx, 32));
        float e0 = __expf(s[0] - mx), e1 = __expf(s[1] - mx);
        float e2 = __expf(s[2] - mx), e3 = __expf(s[3] - mx);
        float sm = e0 + e1 + e2 + e3;
        sm += __shfl_xor(sm, 16);
        sm += __shfl_xor(sm, 32);
        float inv = 1.0f / sm;
        bf16x4 pf;
        pf[0] = (short)f2bf(e0 * inv); pf[1] = (short)f2bf(e1 * inv);
        pf[2] = (short)f2bf(e2 * inv); pf[3] = (short)f2bf(e3 * inv);

        // outT -> the position's own (dead) stage slot, same swizzle
        #pragma unroll
        for (int ct = 0; ct < 8; ++ct) {
            f32x4 z = (f32x4){0.f, 0.f, 0.f, 0.f};
            z = __builtin_amdgcn_mfma_f32_16x16x16bf16_1k(vreg[ct], pf, z, 0, 0, 0);
            bf16x4 ob;
            #pragma unroll
            for (int rr = 0; rr < 4; ++rr) ob[rr] = (short)f2bf(z[rr]);
            *(bf16x4*)&buf[IDX_X(pos, lr, (ct * 16 + grp * 4) ^ swz)] = ob;
        }
    }
    __syncthreads();   // B2: all outT slots visible

    // ---- P5: y = gamma*out + x (exact fp32 residual); 128B pieces -----------
    // SERIAL r-loop + rolling 8-deep halves: max 32 transient VGPRs.
    for (int r = 0; r < 2; ++r) {
        const int cs  = cs0 + 64 * r;
        const int loc = cs ^ (seg << 3);   // matches writer: pos>>2 == seg here
        const float* xrow = xb + (size_t)cs * THW + seg * 4;
        float*       yrow = yb + (size_t)cs * THW + seg * 4;
        #pragma unroll
        for (int half = 0; half < 2; ++half) {
            const int t0 = half * 8;
            f32x4 xa[8];
            #pragma unroll
            for (int t = 0; t < 8; ++t) xa[t] = *(const f32x4*)(xrow + (t0 + t) * HW_);
            #pragma unroll
            for (int t = 0; t < 8; ++t) {
                f32x4 rv;
                #pragma unroll
                for (int e = 0; e < 4; ++e)
                    rv[e] = fmaf(g, bf2f(buf[IDX_X(seg * 4 + e, t0 + t, loc)]), xa[t][e]);
                *(f32x4*)(yrow + (t0 + t) * HW_) = rv;
            }
        }
    }
}

// ---------------- launch --------------------------------------------------------
extern "C" void kernel_launch(void* const* d_in, const int* in_sizes, int n_in,
                              void* d_out, int out_size, void* d_ws, size_t ws_size,
                              hipStream_t stream) {
    const float* x  = (const float*)d_in[0];
    const float* qw = (const float*)d_in[1];
    const float* qb = (const float*)d_in[2];
    const float* kw = (const float*)d_in[3];
    const float* kb = (const float*)d_in[4];
    const float* vw = (const float*)d_in[5];
    const float* vb = (const float*)d_in[6];
    const float* gm = (const float*)d_in[7];
    float* y = (float*)d_out;

    unsigned short* W2 = (unsigned short*)d_ws;                  // 160*128 bf16
    float* b2 = (float*)((char*)d_ws + CO_ * C_ * sizeof(unsigned short));

    tsa_prepack<<<80, 256, 0, stream>>>(qw, qb, kw, kb, vw, vb, W2, b2);
    tsa_main<<<NBLK, 512, 0, stream>>>(x, W2, b2, gm, y);
}

// Round 14
// 84.020 us; speedup vs baseline: 1.2071x; 1.0484x over previous
//
#include <hip/hip_runtime.h>

// TSA_24936580121000 — fused temporal self-attention, MI355X gfx950. Round 14.
// = Round 13 (88us, clean traffic, 128B grain) + weight-load economy:
//  (1) P2 processes positions in PAIRS sharing each wf fragment: W-fragment
//      VMEM instrs per wave drop 640 -> 80 (R13 reloaded all 40 frags per
//      position; 5120 instrs/CU/block thrashing 40KB W2 through 32KB L1).
//  (2) W3 prepack: fragments stored lane-contiguous, so a wave's (nt,ks) load
//      is one coalesced 1KB piece (8 L1 lines vs 16 scattered).
//  (3) P5's first residual batch pre-issued before B2.
// Grain (WT=32 / 128B pieces), LDS plan, 2 barriers, swizzles: unchanged.

#define C_  128
#define T_  16
#define H_  64
#define W_  64
#define HW_ (H_*W_)
#define CO_ 160          // 16 q + 16 k + 128 v
#define WT_ 32           // w positions per block
#define NBLK 512         // 4 b * 64 h * 2 wtiles
#define THW (T_*H_*W_)

typedef float  f32x4  __attribute__((ext_vector_type(4)));
typedef short  bf16x4 __attribute__((ext_vector_type(4)));
typedef short  bf16x8 __attribute__((ext_vector_type(8)));

__device__ __forceinline__ unsigned short f2bf(float f) {
    union { float f; unsigned u; } v; v.f = f;
    unsigned r = v.u + 0x7fffu + ((v.u >> 16) & 1u);   // RNE
    return (unsigned short)(r >> 16);
}
__device__ __forceinline__ float bf2f(unsigned short s) {
    union { unsigned u; float f; } v; v.u = ((unsigned)s) << 16;
    return v.f;
}

// -------- prepack: W2[160][128] bf16 + W3 fragment-contiguous + biases --------
// W3[((nt*4+ks)*64 + lane)*8 + j] = W[nt*16 + (lane&15)][ks*32 + (lane>>4)*8 + j]
__global__ __launch_bounds__(256) void tsa_prepack(
        const float* __restrict__ qw, const float* __restrict__ qb,
        const float* __restrict__ kw, const float* __restrict__ kb,
        const float* __restrict__ vw, const float* __restrict__ vb,
        unsigned short* __restrict__ W2, float* __restrict__ b2,
        unsigned short* __restrict__ W3) {
    int i = blockIdx.x * 256 + threadIdx.x;      // 80*256 == 20480 == 160*128
    int o = i >> 7, c = i & 127;
    float v = (o < 16) ? qw[o * C_ + c] : (o < 32) ? kw[(o - 16) * C_ + c]
                                                   : vw[(o - 32) * C_ + c];
    unsigned short u = f2bf(v);
    W2[i] = u;
    int nt = o >> 4, lr = o & 15, ks = c >> 5, gp = (c >> 3) & 3, j = c & 7;
    W3[(((nt * 4 + ks) * 64) + gp * 16 + lr) * 8 + j] = u;
    if (i < CO_) b2[i] = (i < 16) ? qb[i] : (i < 32) ? kb[i - 16] : vb[i - 32];
}

// ---------------- LDS geometry (shorts) ----------------------------------------
// stage/out (time-shared PER SLOT): [pos=32][t=16][c=128 swz] pos-stride 2184,
//   t-stride 136. c stored XOR-swizzled: loc = c ^ ((pos>>2)<<3).
// qkscr: wave-private [wv=8][qk=2][t=16][o-stride 20]  (no barrier needed)
// bias:  f32[160]
#define PS 2184
#define TS 136
#define IDX_X(pos, t, c)   ((pos) * PS + (t) * TS + (c))
#define QOFF 69888
#define QIDX(wv, qk, t, o) (QOFF + (wv) * 640 + (qk) * 320 + (t) * 20 + (o))
#define BIAS_OFF 75008
#define BUF_SH 75328          // 150656 B <= 160 KiB -> 1 block/CU

// ---------------- main fused kernel --------------------------------------------
__global__ __launch_bounds__(512) void tsa_main(
        const float* __restrict__ x, const unsigned short* __restrict__ W3,
        const float* __restrict__ b2, const float* __restrict__ gamma,
        float* __restrict__ y) {

    __shared__ __align__(16) unsigned short buf[BUF_SH];
    float* bias_lds = (float*)&buf[BIAS_OFF];

    // XCD-chunked swizzle (nwg=512 % 8 == 0)
    int bid  = blockIdx.x;
    int work = (bid & 7) * (NBLK / 8) + (bid >> 3);
    int bh = work >> 1;
    int wt = work & 1;
    int b  = bh >> 6, h = bh & 63;
    int w0 = wt * WT_;

    const size_t base = (size_t)b * C_ * THW + (size_t)h * W_ + w0;
    const float* xb = x + base;
    float*       yb = y + base;

    const int tid  = threadIdx.x;
    const int lane = tid & 63;
    const int seg  = tid & 7;         // 16B segment of the 128B w-row
    const int cs0  = tid >> 3;        // channel 0..63 (+64 on second half)
    const float g  = gamma[0];

    const int wv  = tid >> 6;         // wave 0..7 -> positions wv*4 .. wv*4+3
    const int lr  = tid & 15;
    const int grp = (tid & 63) >> 4;

    if (tid < CO_) bias_lds[tid] = b2[tid];

    // ---- P1: stage x tile -> bf16 LDS [pos][t][c-swz]; 128B read pieces -----
    // SERIAL r-loop: one 8-deep batch in flight at a time.
    for (int r = 0; r < 2; ++r) {
        const int cs  = cs0 + 64 * r;
        const int loc = cs ^ (seg << 3);
        const float* xcol = xb + (size_t)cs * THW + seg * 4;
        f32x4 xa[8];
        #pragma unroll
        for (int t = 0; t < 8; ++t) xa[t] = *(const f32x4*)(xcol + t * HW_);
        #pragma unroll
        for (int t = 0; t < 8; ++t)
            #pragma unroll
            for (int e = 0; e < 4; ++e)
                buf[IDX_X(seg * 4 + e, t, loc)] = f2bf(xa[t][e]);
        #pragma unroll
        for (int t = 0; t < 8; ++t) xa[t] = *(const f32x4*)(xcol + (t + 8) * HW_);
        #pragma unroll
        for (int t = 0; t < 8; ++t)
            #pragma unroll
            for (int e = 0; e < 4; ++e)
                buf[IDX_X(seg * 4 + e, t + 8, loc)] = f2bf(xa[t][e]);
    }
    __syncthreads();   // B1 (one of only two barriers)

    // ---- per-wave: 2 PAIRS of positions; wf fragments shared within a pair ---
    const int swz = wv << 3;          // pos>>2 == wv for this wave's positions
    for (int pr = 0; pr < 2; ++pr) {
        const int posA = wv * 4 + pr * 2;
        const int posB = posA + 1;

        // afrag preload for both positions (slots dead afterwards)
        bf16x8 afA[4], afB[4];
        #pragma unroll
        for (int ks = 0; ks < 4; ++ks) {
            afA[ks] = *(const bf16x8*)&buf[IDX_X(posA, lr, (ks * 32 + grp * 8) ^ swz)];
            afB[ks] = *(const bf16x8*)&buf[IDX_X(posB, lr, (ks * 32 + grp * 8) ^ swz)];
        }

        // qkv projection: ONE wf load feeds TWO MFMAs (A and B)
        bf16x4 vreg[2][8];
        bf16x4 qkB[2];                // pos-B q/k parked in regs during A's P3
        #pragma unroll
        for (int nt = 0; nt < 10; ++nt) {
            f32x4 acc0 = (f32x4){0.f, 0.f, 0.f, 0.f};
            f32x4 acc1 = (f32x4){0.f, 0.f, 0.f, 0.f};
            #pragma unroll
            for (int ks = 0; ks < 4; ++ks) {
                bf16x8 wf = *(const bf16x8*)&W3[(((nt * 4 + ks) * 64) + lane) * 8];
                acc0 = __builtin_amdgcn_mfma_f32_16x16x32_bf16(afA[ks], wf, acc0, 0, 0, 0);
                acc1 = __builtin_amdgcn_mfma_f32_16x16x32_bf16(afB[ks], wf, acc1, 0, 0, 0);
            }
            float bv = bias_lds[nt * 16 + lr];
            if (nt < 2) {
                #pragma unroll
                for (int rr = 0; rr < 4; ++rr)
                    buf[QIDX(wv, nt, grp * 4 + rr, lr)] = f2bf(acc0[rr] + bv);
                bf16x4 pk;
                #pragma unroll
                for (int rr = 0; rr < 4; ++rr) pk[rr] = (short)f2bf(acc1[rr] + bv);
                qkB[nt] = pk;
            } else {
                bf16x4 pA, pB;
                #pragma unroll
                for (int rr = 0; rr < 4; ++rr) {
                    pA[rr] = (short)f2bf(acc0[rr] + bv);
                    pB[rr] = (short)f2bf(acc1[rr] + bv);
                }
                vreg[0][nt - 2] = pA;
                vreg[1][nt - 2] = pB;
            }
        }

        // ---- P3 for A, then park->slot swap, then P3 for B -------------------
        #pragma unroll
        for (int p = 0; p < 2; ++p) {
            const int pos = p ? posB : posA;
            if (p) {   // overwrite slot with B's q/k (A's reads already done)
                #pragma unroll
                for (int rr = 0; rr < 4; ++rr) {
                    buf[QIDX(wv, 0, grp * 4 + rr, lr)] = (unsigned short)qkB[0][rr];
                    buf[QIDX(wv, 1, grp * 4 + rr, lr)] = (unsigned short)qkB[1][rr];
                }
            }
            bf16x4 kf = *(const bf16x4*)&buf[QIDX(wv, 1, lr, grp * 4)];
            bf16x4 qf = *(const bf16x4*)&buf[QIDX(wv, 0, lr, grp * 4)];
            f32x4 s = (f32x4){0.f, 0.f, 0.f, 0.f};
            s = __builtin_amdgcn_mfma_f32_16x16x16bf16_1k(kf, qf, s, 0, 0, 0);
            float mx = fmaxf(fmaxf(s[0], s[1]), fmaxf(s[2], s[3]));
            mx = fmaxf(mx, __shfl_xor(mx, 16));
            mx = fmaxf(mx, __shfl_xor(mx, 32));
            float e0 = __expf(s[0] - mx), e1 = __expf(s[1] - mx);
            float e2 = __expf(s[2] - mx), e3 = __expf(s[3] - mx);
            float sm = e0 + e1 + e2 + e3;
            sm += __shfl_xor(sm, 16);
            sm += __shfl_xor(sm, 32);
            float inv = 1.0f / sm;
            bf16x4 pf;
            pf[0] = (short)f2bf(e0 * inv); pf[1] = (short)f2bf(e1 * inv);
            pf[2] = (short)f2bf(e2 * inv); pf[3] = (short)f2bf(e3 * inv);
            #pragma unroll
            for (int ct = 0; ct < 8; ++ct) {
                f32x4 z = (f32x4){0.f, 0.f, 0.f, 0.f};
                z = __builtin_amdgcn_mfma_f32_16x16x16bf16_1k(vreg[p][ct], pf, z, 0, 0, 0);
                bf16x4 ob;
                #pragma unroll
                for (int rr = 0; rr < 4; ++rr) ob[rr] = (short)f2bf(z[rr]);
                *(bf16x4*)&buf[IDX_X(pos, lr, (ct * 16 + grp * 4) ^ swz)] = ob;
            }
        }
    }

    // ---- pre-issue first residual batch (r=0, t 0..7), then B2 ---------------
    const float* xrow0 = xb + (size_t)cs0 * THW + seg * 4;
    f32x4 pre[8];
    #pragma unroll
    for (int t = 0; t < 8; ++t) pre[t] = *(const f32x4*)(xrow0 + t * HW_);

    __syncthreads();   // B2: all outT slots visible

    // ---- P5: y = gamma*out + x (exact fp32 residual); 128B pieces ------------
    for (int r = 0; r < 2; ++r) {
        const int cs  = cs0 + 64 * r;
        const int loc = cs ^ (seg << 3);   // matches writer: pos>>2 == seg here
        const float* xrow = xb + (size_t)cs * THW + seg * 4;
        float*       yrow = yb + (size_t)cs * THW + seg * 4;
        #pragma unroll
        for (int half = 0; half < 2; ++half) {
            const int t0 = half * 8;
            f32x4 xa[8];
            if (r == 0 && half == 0) {
                #pragma unroll
                for (int t = 0; t < 8; ++t) xa[t] = pre[t];
            } else {
                #pragma unroll
                for (int t = 0; t < 8; ++t) xa[t] = *(const f32x4*)(xrow + (t0 + t) * HW_);
            }
            #pragma unroll
            for (int t = 0; t < 8; ++t) {
                f32x4 rv;
                #pragma unroll
                for (int e = 0; e < 4; ++e)
                    rv[e] = fmaf(g, bf2f(buf[IDX_X(seg * 4 + e, t0 + t, loc)]), xa[t][e]);
                *(f32x4*)(yrow + (t0 + t) * HW_) = rv;
            }
        }
    }
}

// ---------------- launch --------------------------------------------------------
extern "C" void kernel_launch(void* const* d_in, const int* in_sizes, int n_in,
                              void* d_out, int out_size, void* d_ws, size_t ws_size,
                              hipStream_t stream) {
    const float* x  = (const float*)d_in[0];
    const float* qw = (const float*)d_in[1];
    const float* qb = (const float*)d_in[2];
    const float* kw = (const float*)d_in[3];
    const float* kb = (const float*)d_in[4];
    const float* vw = (const float*)d_in[5];
    const float* vb = (const float*)d_in[6];
    const float* gm = (const float*)d_in[7];
    float* y = (float*)d_out;

    unsigned short* W2 = (unsigned short*)d_ws;                        // 40960 B
    float*          b2 = (float*)((char*)d_ws + 40960);                //   640 B
    unsigned short* W3 = (unsigned short*)((char*)d_ws + 41600);       // 40960 B

    tsa_prepack<<<80, 256, 0, stream>>>(qw, qb, kw, kb, vw, vb, W2, b2, W3);
    tsa_main<<<NBLK, 512, 0, stream>>>(x, W3, b2, gm, y);
}